// Round 9
// baseline (336.801 us; speedup 1.0000x reference)
//
#include <hip/hip_runtime.h>
#include <math.h>

#define BB 4
#define CC 256
#define NN 4096
#define DQ 32
#define LOG2E 1.44269504f
#define THR 8.0f

typedef _Float16 half8 __attribute__((ext_vector_type(8)));
typedef _Float16 half4 __attribute__((ext_vector_type(4)));
typedef float float4v __attribute__((ext_vector_type(4)));

// ---------------- prep: W -> f16 (log2e folded into Wq/bq) ----------------
__global__ __launch_bounds__(64) void prep_kernel(
    const float* __restrict__ Wq, const float* __restrict__ bq,
    const float* __restrict__ Wk, const float* __restrict__ bk,
    const float* __restrict__ Wv, const float* __restrict__ bv,
    _Float16* __restrict__ Wh, float* __restrict__ bh)
{
    int o = blockIdx.x, t = threadIdx.x;
    const float* src; float scale = 1.0f, bias;
    if (o < DQ)            { src = Wq + o * CC;        scale = LOG2E; bias = bq[o] * LOG2E; }
    else if (o < 2 * DQ)   { src = Wk + (o - DQ) * CC;                bias = bk[o - DQ]; }
    else                   { src = Wv + (o - 2 * DQ) * CC;            bias = bv[o - 2 * DQ]; }
    float4 v = *(const float4*)(src + t * 4);
    half4 h = { (_Float16)(v.x * scale), (_Float16)(v.y * scale),
                (_Float16)(v.z * scale), (_Float16)(v.w * scale) };
    *(half4*)(Wh + o * CC + t * 4) = h;
    if (t == 0) bh[o] = bias;
}

// ---------------- proj: MFMA GEMM, all 320 outputs x 32-pixel tile ----------------
__global__ __launch_bounds__(256) void proj_kernel(
    const float* __restrict__ x, const _Float16* __restrict__ Wh,
    const float* __restrict__ bh,
    _Float16* __restrict__ Qt, _Float16* __restrict__ Kt,
    _Float16* __restrict__ Vh)
{
    __shared__ _Float16 xl[32 * 256];
    __shared__ _Float16 os_qk[32 * 72];
    __shared__ _Float16 os_v[256 * 40];

    const int tid = threadIdx.x;
    const int lane = tid & 63, w = tid >> 6;
    const int i16 = lane & 15, q = lane >> 4;
    const int n0 = blockIdx.x * 32, b = blockIdx.y;

    const float* xb = x + (size_t)b * CC * NN + n0;
    #pragma unroll
    for (int u = 0; u < 8; ++u) {
        int idx = u * 256 + tid;
        int c = idx >> 3, n4 = idx & 7;
        float4 v = *(const float4*)(xb + (size_t)c * NN + n4 * 4);
        int chunk = c >> 3, cl = c & 7;
        float vv[4] = {v.x, v.y, v.z, v.w};
        #pragma unroll
        for (int e = 0; e < 4; ++e) {
            int n = n4 * 4 + e;
            xl[n * 256 + ((chunk ^ n) * 8) + cl] = (_Float16)vv[e];
        }
    }

    float4v acc[5][2];
    const int obase = 80 * w;
    #pragma unroll
    for (int ot = 0; ot < 5; ++ot) {
        float4 b4 = *(const float4*)(bh + obase + 16 * ot + 4 * q);
        #pragma unroll
        for (int nt = 0; nt < 2; ++nt)
            acc[ot][nt] = (float4v){b4.x, b4.y, b4.z, b4.w};
    }
    __syncthreads();

    #pragma unroll
    for (int k = 0; k < 8; ++k) {
        half8 af[5], bf[2];
        #pragma unroll
        for (int ot = 0; ot < 5; ++ot)
            af[ot] = *(const half8*)(Wh + (size_t)(obase + 16 * ot + i16) * CC + k * 32 + 8 * q);
        #pragma unroll
        for (int nt = 0; nt < 2; ++nt) {
            int n = 16 * nt + i16;
            bf[nt] = *(const half8*)&xl[n * 256 + (((4 * k + q) ^ n) * 8)];
        }
        #pragma unroll
        for (int ot = 0; ot < 5; ++ot)
            #pragma unroll
            for (int nt = 0; nt < 2; ++nt)
                acc[ot][nt] = __builtin_amdgcn_mfma_f32_16x16x32_f16(af[ot], bf[nt], acc[ot][nt], 0, 0, 0);
    }

    #pragma unroll
    for (int ot = 0; ot < 5; ++ot) {
        int og = obase + 16 * ot;
        #pragma unroll
        for (int nt = 0; nt < 2; ++nt) {
            int n = 16 * nt + i16;
            if (og < 64) {
                half4 hv = { (_Float16)acc[ot][nt][0], (_Float16)acc[ot][nt][1],
                             (_Float16)acc[ot][nt][2], (_Float16)acc[ot][nt][3] };
                *(half4*)&os_qk[n * 72 + og + 4 * q] = hv;
            } else {
                int cb = og - 64 + 4 * q;
                #pragma unroll
                for (int r = 0; r < 4; ++r)
                    os_v[(cb + r) * 40 + n] = (_Float16)acc[ot][nt][r];
            }
        }
    }
    __syncthreads();

    _Float16* Qtb = Qt + (size_t)b * NN * DQ;
    _Float16* Ktb = Kt + (size_t)b * NN * DQ;
    {
        int n = tid >> 3, p = tid & 7;
        half8 hv = *(const half8*)&os_qk[n * 72 + 8 * p];
        if (p < 4) *(half8*)(Qtb + (size_t)(n0 + n) * DQ + 8 * p) = hv;
        else       *(half8*)(Ktb + (size_t)(n0 + n) * DQ + 8 * (p - 4)) = hv;
    }
    _Float16* Vb = Vh + (size_t)b * CC * NN;
    #pragma unroll
    for (int u = 0; u < 4; ++u) {
        int c = u * 64 + (tid >> 2), p = tid & 3;
        half8 hv = *(const half8*)&os_v[c * 40 + 8 * p];
        *(half8*)(Vb + (size_t)c * NN + n0 + 8 * p) = hv;
    }
}

// ---------------- attn: x16-identity, key-split, deferred-max, barrier-free loop ----
// 32q x 256c blocks, 4 waves, grid 512 (XCD-bijective: each XCD owns (b, i-half)
// so V[b] 2MB + K 256KB are L2-resident). mfma_16x16x16 identity: S^T = mfma(K,Q)
// puts P'[key 4q+r][query i16] exactly where PV's B-frag needs it -> no P LDS,
// no barriers, S computed ONCE (no prepass). Wave w owns keys strip [64t+16w,+16),
// all 256 channels; per-wave online (m,l,O) with deferred-max (THR=8, rescale
// only when tile max exceeds m_ref+8, ~7x per 64 tiles); partials merged in the
// epilogue with factors 2^(m_w - m). K/V fragments direct from global (L2),
// double-buffered 2 tiles deep in regs.
__global__ __launch_bounds__(256, 2) void attn_kernel(
    const float* __restrict__ x,
    const _Float16* __restrict__ Qt, const _Float16* __restrict__ Kt,
    const _Float16* __restrict__ Vh,
    float* __restrict__ out)
{
    __shared__ float slab[32 * 264];     // O combine: [query][c + pad]
    __shared__ float stx_m[4][32];
    __shared__ float stx_l[4][32];
    __shared__ float linv_s[32];

    const int tid = threadIdx.x;
    const int w = tid >> 6, lane = tid & 63;
    const int i16 = lane & 15, q = lane >> 4;

    const int wgid = blockIdx.x;         // 512 blocks
    const int xcd = wgid & 7;
    const int b = xcd >> 1;
    const int i0 = ((xcd & 1) * 64 + (wgid >> 3)) * 32;

    const char* Kcur = (const char*)(Kt + (size_t)b * NN * DQ);
    const char* Vcur = (const char*)(Vh + (size_t)b * CC * NN);

    // Q frags (x16): qh[it][h] = Q[query 16it+i16][d = 16h+4q+e]
    half4 qh[2][2];
    {
        const _Float16* Qtb = Qt + (size_t)b * NN * DQ;
        #pragma unroll
        for (int it = 0; it < 2; ++it)
            #pragma unroll
            for (int h = 0; h < 2; ++h)
                qh[it][h] = *(const half4*)(Qtb + (size_t)(i0 + 16 * it + i16) * DQ + 16 * h + 4 * q);
    }

    // per-lane byte offsets (uniform parts stay in pointers -> SGPR)
    const unsigned vloff = (unsigned)((i16 * NN + 16 * w + 4 * q) * 2);
    const unsigned kloff = (unsigned)(((16 * w + i16) * DQ + 4 * q) * 2);

    float4v O[16][2];
    #pragma unroll
    for (int ct = 0; ct < 16; ++ct)
        #pragma unroll
        for (int it = 0; it < 2; ++it)
            O[ct][it] = (float4v){0.f, 0.f, 0.f, 0.f};
    float m_ref[2] = {-INFINITY, -INFINITY};
    float lB[2]    = {0.f, 0.f};

    half4 vA[16], vB[16], kA0, kA1, kB0, kB1;

    auto LOADV = [&](half4* vv) {
        #pragma unroll
        for (int u = 0; u < 16; ++u)
            vv[u] = *(const half4*)(Vcur + u * 131072 + vloff);   // 16 rows apart = 16*NN*2
        Vcur += 128;                                              // next 64-key tile
    };
    auto LOADK = [&](half4& k0, half4& k1) {
        k0 = *(const half4*)(Kcur + kloff);
        k1 = *(const half4*)(Kcur + kloff + 32);
        Kcur += 4096;                                             // 64 keys * 64B
    };
    auto TILE = [&](const half4* vv, half4 k0, half4 k1) {
        // S^T strip: lane (i16,q) -> S[key 4q+r][query i16]
        float4v s[2];
        #pragma unroll
        for (int it = 0; it < 2; ++it) {
            float4v z = {0.f, 0.f, 0.f, 0.f};
            float4v a = __builtin_amdgcn_mfma_f32_16x16x16f16(k0, qh[it][0], z, 0, 0, 0);
            s[it] = __builtin_amdgcn_mfma_f32_16x16x16f16(k1, qh[it][1], a, 0, 0, 0);
        }
        float pmax[2];
        #pragma unroll
        for (int it = 0; it < 2; ++it) {
            float mx = fmaxf(fmaxf(s[it][0], s[it][1]), fmaxf(s[it][2], s[it][3]));
            mx = fmaxf(mx, __shfl_xor(mx, 16, 64));
            mx = fmaxf(mx, __shfl_xor(mx, 32, 64));
            pmax[it] = mx;
        }
        if (__any((pmax[0] > m_ref[0] + THR) || (pmax[1] > m_ref[1] + THR))) {
            #pragma unroll
            for (int it = 0; it < 2; ++it) {
                float mn = fmaxf(m_ref[it], pmax[it]);
                float al = exp2f(m_ref[it] - mn);   // 1.0 exactly when unchanged
                #pragma unroll
                for (int ct = 0; ct < 16; ++ct)
                    O[ct][it] *= al;
                lB[it] *= al;
                m_ref[it] = mn;
            }
        }
        half4 pb[2];
        #pragma unroll
        for (int it = 0; it < 2; ++it) {
            float p0 = exp2f(s[it][0] - m_ref[it]);
            float p1 = exp2f(s[it][1] - m_ref[it]);
            float p2 = exp2f(s[it][2] - m_ref[it]);
            float p3 = exp2f(s[it][3] - m_ref[it]);
            lB[it] += (p0 + p1) + (p2 + p3);
            pb[it] = (half4){ (_Float16)p0, (_Float16)p1, (_Float16)p2, (_Float16)p3 };
        }
        // PV: S-output frag IS the B-frag (identity); V frag direct from regs
        __builtin_amdgcn_s_setprio(1);
        #pragma unroll
        for (int ct = 0; ct < 16; ++ct)
            #pragma unroll
            for (int it = 0; it < 2; ++it)
                O[ct][it] = __builtin_amdgcn_mfma_f32_16x16x16f16(vv[ct], pb[it], O[ct][it], 0, 0, 0);
        __builtin_amdgcn_s_setprio(0);
    };

    // prologue: tiles 0,1 in regs
    LOADK(kA0, kA1); LOADV(vA);
    LOADK(kB0, kB1); LOADV(vB);

    for (int tt = 0; tt < 64; tt += 2) {
        TILE(vA, kA0, kA1);
        if (tt + 2 < 64) { LOADV(vA); LOADK(kA0, kA1); }
        TILE(vB, kB0, kB1);
        if (tt + 3 < 64) { LOADV(vB); LOADK(kB0, kB1); }
    }

    // ---- epilogue: merge per-wave (m,l,O) ----
    #pragma unroll
    for (int it = 0; it < 2; ++it) {
        lB[it] += __shfl_xor(lB[it], 16, 64);
        lB[it] += __shfl_xor(lB[it], 32, 64);
    }
    if (q == 0) {
        #pragma unroll
        for (int it = 0; it < 2; ++it) {
            stx_m[w][16 * it + i16] = m_ref[it];
            stx_l[w][16 * it + i16] = lB[it];
        }
    }
    __syncthreads();

    float ffac[2];
    #pragma unroll
    for (int it = 0; it < 2; ++it) {
        int r = 16 * it + i16;
        float mf = fmaxf(fmaxf(stx_m[0][r], stx_m[1][r]), fmaxf(stx_m[2][r], stx_m[3][r]));
        float lf = stx_l[0][r] * exp2f(stx_m[0][r] - mf)
                 + stx_l[1][r] * exp2f(stx_m[1][r] - mf)
                 + stx_l[2][r] * exp2f(stx_m[2][r] - mf)
                 + stx_l[3][r] * exp2f(stx_m[3][r] - mf);
        ffac[it] = exp2f(m_ref[it] - mf);
        if (w == 0 && q == 0) linv_s[r] = 1.0f / lf;
    }

    // serialized cross-wave O accumulation into slab
    #pragma unroll
    for (int rd = 0; rd < 4; ++rd) {
        if (w == rd) {
            #pragma unroll
            for (int ct = 0; ct < 16; ++ct)
                #pragma unroll
                for (int it = 0; it < 2; ++it) {
                    float* p = &slab[(16 * it + i16) * 264 + 16 * ct + 4 * q];
                    float4v val = O[ct][it] * ffac[it];
                    if (rd == 0) *(float4v*)p = val;
                    else         *(float4v*)p = *(const float4v*)p + val;
                }
        }
        __syncthreads();
    }

    // final: out = x + slab * linv
    const float* xb = x + (size_t)b * CC * NN;
    float* ob = out + (size_t)b * CC * NN;
    const int nq = tid & 7;
    #pragma unroll
    for (int u = 0; u < 8; ++u) {
        int c = 32 * u + (tid >> 3);
        float rs[4];
        #pragma unroll
        for (int e = 0; e < 4; ++e) {
            int i = 4 * nq + e;
            rs[e] = slab[i * 264 + c] * linv_s[i];
        }
        size_t idx = (size_t)c * NN + i0 + 4 * nq;
        float4 xv = *(const float4*)(xb + idx);
        float4 o4 = { xv.x + rs[0], xv.y + rs[1], xv.z + rs[2], xv.w + rs[3] };
        *(float4*)(ob + idx) = o4;
    }
}

extern "C" void kernel_launch(void* const* d_in, const int* in_sizes, int n_in,
                              void* d_out, int out_size, void* d_ws, size_t ws_size,
                              hipStream_t stream) {
    const float* x  = (const float*)d_in[0];
    const float* Wq = (const float*)d_in[1];
    const float* bq = (const float*)d_in[2];
    const float* Wk = (const float*)d_in[3];
    const float* bk = (const float*)d_in[4];
    const float* Wv = (const float*)d_in[5];
    const float* bv = (const float*)d_in[6];
    float* out = (float*)d_out;

    char* ws = (char*)d_ws;
    _Float16* Wh = (_Float16*)(ws);                 // 320*256*2 = 163840
    float*    bh = (float*)(ws + 163840);           // 1280
    _Float16* Qt = (_Float16*)(ws + 262144);        // 4*4096*32*2 = 1 MB
    _Float16* Kt = (_Float16*)(ws + 1310720);       // 1 MB
    _Float16* Vh = (_Float16*)(ws + 2359296);       // 4*256*4096*2 = 8 MB

    prep_kernel<<<dim3(320), 64, 0, stream>>>(Wq, bq, Wk, bk, Wv, bv, Wh, bh);
    proj_kernel<<<dim3(NN / 32, BB), 256, 0, stream>>>(x, Wh, bh, Qt, Kt, Vh);
    attn_kernel<<<dim3(512), 256, 0, stream>>>(x, Qt, Kt, Vh, out);
}

// Round 11
// 253.527 us; speedup vs baseline: 1.3285x; 1.3285x over previous
//
#include <hip/hip_runtime.h>
#include <math.h>

#define BB 4
#define CC 256
#define NN 4096
#define DQ 32
#define LOG2E 1.44269504f

typedef _Float16 half8 __attribute__((ext_vector_type(8)));
typedef _Float16 half4 __attribute__((ext_vector_type(4)));
typedef float float4v __attribute__((ext_vector_type(4)));

// ---------------- prep: W -> f16 (log2e folded into Wq/bq) ----------------
__global__ __launch_bounds__(64) void prep_kernel(
    const float* __restrict__ Wq, const float* __restrict__ bq,
    const float* __restrict__ Wk, const float* __restrict__ bk,
    const float* __restrict__ Wv, const float* __restrict__ bv,
    _Float16* __restrict__ Wh, float* __restrict__ bh)
{
    int o = blockIdx.x, t = threadIdx.x;
    const float* src; float scale = 1.0f, bias;
    if (o < DQ)            { src = Wq + o * CC;        scale = LOG2E; bias = bq[o] * LOG2E; }
    else if (o < 2 * DQ)   { src = Wk + (o - DQ) * CC;                bias = bk[o - DQ]; }
    else                   { src = Wv + (o - 2 * DQ) * CC;            bias = bv[o - 2 * DQ]; }
    float4 v = *(const float4*)(src + t * 4);
    half4 h = { (_Float16)(v.x * scale), (_Float16)(v.y * scale),
                (_Float16)(v.z * scale), (_Float16)(v.w * scale) };
    *(half4*)(Wh + o * CC + t * 4) = h;
    if (t == 0) bh[o] = bias;
}

// ---------------- proj2: 8-wave, 32-pixel tile; wave owns 5 of 40 (ot,nt) pairs ----------------
// Same math/layout as the verified 4-wave proj; 512 threads halve per-wave
// serial MFMA (80->40) and per-thread staging scatter (32->16 writes).
// LDS 41KB -> 2-3 blocks/CU co-resident -> 4-6 waves/SIMD latency hiding.
__global__ __launch_bounds__(512) void proj_kernel(
    const float* __restrict__ x, const _Float16* __restrict__ Wh,
    const float* __restrict__ bh,
    _Float16* __restrict__ Qt, _Float16* __restrict__ Kt,
    _Float16* __restrict__ Vh)
{
    __shared__ _Float16 xl[32 * 256];
    __shared__ _Float16 os_qk[32 * 72];
    __shared__ _Float16 os_v[256 * 40];

    const int tid = threadIdx.x;
    const int lane = tid & 63, w = tid >> 6;      // w in 0..7
    const int i16 = lane & 15, q = lane >> 4;
    const int n0 = blockIdx.x * 32, b = blockIdx.y;

    // stage x tile transposed to f16 [n][c] with swizzle (16 scatter writes/thread)
    const float* xb = x + (size_t)b * CC * NN + n0;
    #pragma unroll
    for (int u = 0; u < 4; ++u) {
        int idx = u * 512 + tid;
        int c = idx >> 3, n4 = idx & 7;
        float4 v = *(const float4*)(xb + (size_t)c * NN + n4 * 4);
        int chunk = c >> 3, cl = c & 7;
        float vv[4] = {v.x, v.y, v.z, v.w};
        #pragma unroll
        for (int e = 0; e < 4; ++e) {
            int n = n4 * 4 + e;
            xl[n * 256 + ((chunk ^ n) * 8) + cl] = (_Float16)vv[e];
        }
    }

    // pair p = 5w + j; ot = p>>1 (o-tile of 16), nt = p&1 (n-tile of 16)
    float4v acc[5];
    int otj[5], ntj[5];
    #pragma unroll
    for (int j = 0; j < 5; ++j) {
        int p = 5 * w + j;
        otj[j] = p >> 1;
        ntj[j] = p & 1;
        float4 b4 = *(const float4*)(bh + 16 * otj[j] + 4 * q);
        acc[j] = (float4v){b4.x, b4.y, b4.z, b4.w};
    }
    __syncthreads();

    // K loop: 8 steps of 32 channels, 5 MFMA/wave/step
    #pragma unroll
    for (int k = 0; k < 8; ++k) {
        half8 bf[2];
        #pragma unroll
        for (int nt = 0; nt < 2; ++nt) {
            int n = 16 * nt + i16;
            bf[nt] = *(const half8*)&xl[n * 256 + (((4 * k + q) ^ n) * 8)];
        }
        #pragma unroll
        for (int j = 0; j < 5; ++j) {
            half8 af = *(const half8*)(Wh + (size_t)(16 * otj[j] + i16) * CC + k * 32 + 8 * q);
            acc[j] = __builtin_amdgcn_mfma_f32_16x16x32_f16(af, bf[ntj[j]], acc[j], 0, 0, 0);
        }
    }

    // epilogue: write D into transpose buffers
    #pragma unroll
    for (int j = 0; j < 5; ++j) {
        int og = 16 * otj[j];
        int n = 16 * ntj[j] + i16;
        if (og < 64) {   // Q/K rows
            half4 hv = { (_Float16)acc[j][0], (_Float16)acc[j][1],
                         (_Float16)acc[j][2], (_Float16)acc[j][3] };
            *(half4*)&os_qk[n * 72 + og + 4 * q] = hv;
        } else {         // V rows
            int cb = og - 64 + 4 * q;
            #pragma unroll
            for (int r = 0; r < 4; ++r)
                os_v[(cb + r) * 40 + n] = (_Float16)acc[j][r];
        }
    }
    __syncthreads();

    // coalesced global stores
    _Float16* Qtb = Qt + (size_t)b * NN * DQ;
    _Float16* Ktb = Kt + (size_t)b * NN * DQ;
    if (tid < 256) {
        int n = tid >> 3, p = tid & 7;
        half8 hv = *(const half8*)&os_qk[n * 72 + 8 * p];
        if (p < 4) *(half8*)(Qtb + (size_t)(n0 + n) * DQ + 8 * p) = hv;
        else       *(half8*)(Ktb + (size_t)(n0 + n) * DQ + 8 * (p - 4)) = hv;
    }
    _Float16* Vb = Vh + (size_t)b * CC * NN;
    #pragma unroll
    for (int u = 0; u < 2; ++u) {
        int c = u * 128 + (tid >> 2), p = tid & 3;
        half8 hv = *(const half8*)&os_v[c * 40 + 8 * p];
        *(half8*)(Vb + (size_t)c * NN + n0 + 8 * p) = hv;
    }
}

// ---------------- attn: max-only prepass + pipelined PV with inline l (r5-verified) ----------------
// Pass M (barrier-free, NO exp2): wave w streams keys [1024w,1024w+1024) as
// direct A-fragments, per-query running max only (4 MFMA + 16 fmax per tile).
// Combine: shfl over q-quads + 1KB LDS exchange + 1 barrier -> m2v[4].
// Pass B: round-3 verified 1-barrier pipelined loop; l accumulated from the
// f32 P' values already computed there. linv applied in epilogue.
__global__ __launch_bounds__(256) void attn_kernel(
    const float* __restrict__ x,
    const _Float16* __restrict__ Qt, const _Float16* __restrict__ Kt,
    const _Float16* __restrict__ Vh,
    float* __restrict__ out)
{
    __shared__ _Float16 k_lds[2][64 * 32];    // [j][d], d-chunk ^= (j&3)
    __shared__ _Float16 v_lds[3][128 * 64];   // [c][j], j-chunk ^= (c&7)
    __shared__ _Float16 ps[2][64 * 72];       // P': [i][j + pad]
    __shared__ float    stx[4][64];           // cross-wave exchange (m, then l)

    const int tid = threadIdx.x;
    const int w = tid >> 6, lane = tid & 63;
    const int i16 = lane & 15, q = lane >> 4;
    const int i0 = blockIdx.x * 64, cs = blockIdx.y, b = blockIdx.z;
    const int c0 = cs * 128;

    const _Float16* Ktb = Kt + (size_t)b * NN * DQ;
    const _Float16* Vb  = Vh + (size_t)b * CC * NN + (size_t)c0 * NN;

    half8 qb[4];
    {
        const _Float16* Qtb = Qt + (size_t)b * NN * DQ;
        #pragma unroll
        for (int it = 0; it < 4; ++it)
            qb[it] = *(const half8*)(Qtb + (size_t)(i0 + 16 * it + i16) * DQ + 8 * q);
    }

    // ---- pass M: per-query max over this wave's key quarter (no exp2) ----
    float mA[4] = {-INFINITY, -INFINITY, -INFINITY, -INFINITY};
    {
        const _Float16* kq = Ktb + (size_t)(1024 * w) * DQ;
        half8 kf0 = *(const half8*)(kq + (size_t)i16 * DQ + 8 * q);
        half8 kf1 = *(const half8*)(kq + (size_t)(16 + i16) * DQ + 8 * q);
        for (int t = 0; t < 64; t += 2) {
            {
                half8 ka = kf0;
                if (t + 2 < 64)
                    kf0 = *(const half8*)(kq + (size_t)(16 * (t + 2) + i16) * DQ + 8 * q);
                #pragma unroll
                for (int it = 0; it < 4; ++it) {
                    float4v z = {0.f, 0.f, 0.f, 0.f};
                    float4v s = __builtin_amdgcn_mfma_f32_16x16x32_f16(ka, qb[it], z, 0, 0, 0);
                    mA[it] = fmaxf(mA[it], fmaxf(fmaxf(s[0], s[1]), fmaxf(s[2], s[3])));
                }
            }
            {
                half8 ka = kf1;
                if (t + 3 < 64)
                    kf1 = *(const half8*)(kq + (size_t)(16 * (t + 3) + i16) * DQ + 8 * q);
                #pragma unroll
                for (int it = 0; it < 4; ++it) {
                    float4v z = {0.f, 0.f, 0.f, 0.f};
                    float4v s = __builtin_amdgcn_mfma_f32_16x16x32_f16(ka, qb[it], z, 0, 0, 0);
                    mA[it] = fmaxf(mA[it], fmaxf(fmaxf(s[0], s[1]), fmaxf(s[2], s[3])));
                }
            }
        }
        #pragma unroll
        for (int it = 0; it < 4; ++it) {
            mA[it] = fmaxf(mA[it], __shfl_xor(mA[it], 16, 64));
            mA[it] = fmaxf(mA[it], __shfl_xor(mA[it], 32, 64));
        }
        if (q == 0) {
            #pragma unroll
            for (int it = 0; it < 4; ++it)
                stx[w][16 * it + i16] = mA[it];
        }
    }
    __syncthreads();

    float m2v[4];
    #pragma unroll
    for (int it = 0; it < 4; ++it) {
        int qrow = 16 * it + i16;
        m2v[it] = fmaxf(fmaxf(stx[0][qrow], stx[1][qrow]),
                        fmaxf(stx[2][qrow], stx[3][qrow]));
    }

    // ---- pass B: software-pipelined PV loop (round-3 verified) + inline l ----
    float4v O[2][4];
    #pragma unroll
    for (int ct = 0; ct < 2; ++ct)
        #pragma unroll
        for (int it = 0; it < 4; ++it)
            O[ct][it] = (float4v){0.f, 0.f, 0.f, 0.f};
    float lB[4] = {0.f, 0.f, 0.f, 0.f};

    const int jK = tid >> 2, dgK = tid & 3;      // K: 1 half8/thread
    const int cbV = tid >> 3, jgV = tid & 7;     // V: 4 half8/thread
    const int kaddr = jK * 32 + ((dgK ^ (jK & 3)) * 8);
    int vaddr[4];
    #pragma unroll
    for (int u = 0; u < 4; ++u) {
        int c = u * 32 + cbV;
        vaddr[u] = c * 64 + ((jgV ^ (c & 7)) * 8);
    }

    half8 kv, vv[4];
    kv = *(const half8*)(Ktb + (size_t)jK * DQ + 8 * dgK);
    #pragma unroll
    for (int u = 0; u < 4; ++u)
        vv[u] = *(const half8*)(Vb + (size_t)(u * 32 + cbV) * NN + 8 * jgV);
    *(half8*)&k_lds[0][kaddr] = kv;
    #pragma unroll
    for (int u = 0; u < 4; ++u)
        *(half8*)&v_lds[0][vaddr[u]] = vv[u];
    kv = *(const half8*)(Ktb + (size_t)(64 + jK) * DQ + 8 * dgK);
    #pragma unroll
    for (int u = 0; u < 4; ++u)
        vv[u] = *(const half8*)(Vb + (size_t)(u * 32 + cbV) * NN + 64 + 8 * jgV);

    for (int t = 0; t <= 64; ++t) {
        __syncthreads();
        // stage tile t+1 from regs (loaded at iter t-1)
        if (t < 63) {
            *(half8*)&k_lds[(t + 1) & 1][kaddr] = kv;
            const int vn = (t + 1) % 3;
            #pragma unroll
            for (int u = 0; u < 4; ++u)
                *(half8*)&v_lds[vn][vaddr[u]] = vv[u];
        }
        // issue prefetch of tile t+2 (drained by next barrier; covers S+PV)
        if (t < 62) {
            int jn = (t + 2) * 64;
            kv = *(const half8*)(Ktb + (size_t)(jn + jK) * DQ + 8 * dgK);
            #pragma unroll
            for (int u = 0; u < 4; ++u)
                vv[u] = *(const half8*)(Vb + (size_t)(u * 32 + cbV) * NN + jn + 8 * jgV);
        }
        // PV(t-1): inputs were completed before this iter's barrier
        if (t > 0) {
            const _Float16* psp = ps[(t - 1) & 1];
            const _Float16* vp  = v_lds[(t - 1) % 3];
            half8 pb[2][4];
            #pragma unroll
            for (int ks = 0; ks < 2; ++ks)
                #pragma unroll
                for (int it = 0; it < 4; ++it)
                    pb[ks][it] = *(const half8*)&psp[(16 * it + i16) * 72 + 32 * ks + 8 * q];
            __builtin_amdgcn_s_setprio(1);
            #pragma unroll
            for (int ct = 0; ct < 2; ++ct) {
                int c = 32 * w + 16 * ct + i16;
                #pragma unroll
                for (int ks = 0; ks < 2; ++ks) {
                    int g = 4 * ks + q;
                    half8 va = *(const half8*)&vp[c * 64 + ((g ^ (c & 7)) * 8)];
                    #pragma unroll
                    for (int it = 0; it < 4; ++it)
                        O[ct][it] = __builtin_amdgcn_mfma_f32_16x16x32_f16(va, pb[ks][it], O[ct][it], 0, 0, 0);
                }
            }
            __builtin_amdgcn_s_setprio(0);
        }
        // S(t) -> ps[t&1]; accumulate l from the f32 P' values
        if (t < 64) {
            int j = 16 * w + i16;
            half8 ka = *(const half8*)&k_lds[t & 1][j * 32 + ((q ^ (j & 3)) * 8)];
            _Float16* psc = ps[t & 1];
            #pragma unroll
            for (int it = 0; it < 4; ++it) {
                float4v z = {0.f, 0.f, 0.f, 0.f};
                float4v s = __builtin_amdgcn_mfma_f32_16x16x32_f16(ka, qb[it], z, 0, 0, 0);
                float p0 = exp2f(s[0] - m2v[it]);
                float p1 = exp2f(s[1] - m2v[it]);
                float p2 = exp2f(s[2] - m2v[it]);
                float p3 = exp2f(s[3] - m2v[it]);
                lB[it] += (p0 + p1) + (p2 + p3);
                half4 hv = { (_Float16)p0, (_Float16)p1, (_Float16)p2, (_Float16)p3 };
                *(half4*)&psc[(16 * it + i16) * 72 + 16 * w + 4 * q] = hv;
            }
        }
    }

    // reduce l: over q-quads (keys 4q+r), then across waves (key strips)
    #pragma unroll
    for (int it = 0; it < 4; ++it) {
        lB[it] += __shfl_xor(lB[it], 16, 64);
        lB[it] += __shfl_xor(lB[it], 32, 64);
    }
    if (q == 0) {
        #pragma unroll
        for (int it = 0; it < 4; ++it)
            stx[w][16 * it + i16] = lB[it];
    }
    __syncthreads();
    float linv[4];
    #pragma unroll
    for (int it = 0; it < 4; ++it) {
        int qrow = 16 * it + i16;
        linv[it] = 1.0f / ((stx[0][qrow] + stx[1][qrow]) + (stx[2][qrow] + stx[3][qrow]));
    }

    // epilogue: O * (1/l) + residual
    const float* xb = x + (size_t)b * CC * NN;
    float* ob = out + (size_t)b * CC * NN;
    #pragma unroll
    for (int ct = 0; ct < 2; ++ct)
        #pragma unroll
        for (int it = 0; it < 4; ++it)
            #pragma unroll
            for (int r = 0; r < 4; ++r) {
                int c = c0 + 32 * w + 16 * ct + 4 * q + r;
                size_t idx = (size_t)c * NN + i0 + 16 * it + i16;
                ob[idx] = xb[idx] + O[ct][it][r] * linv[it];
            }
}

extern "C" void kernel_launch(void* const* d_in, const int* in_sizes, int n_in,
                              void* d_out, int out_size, void* d_ws, size_t ws_size,
                              hipStream_t stream) {
    const float* x  = (const float*)d_in[0];
    const float* Wq = (const float*)d_in[1];
    const float* bq = (const float*)d_in[2];
    const float* Wk = (const float*)d_in[3];
    const float* bk = (const float*)d_in[4];
    const float* Wv = (const float*)d_in[5];
    const float* bv = (const float*)d_in[6];
    float* out = (float*)d_out;

    char* ws = (char*)d_ws;
    _Float16* Wh = (_Float16*)(ws);                 // 320*256*2 = 163840
    float*    bh = (float*)(ws + 163840);           // 1280
    _Float16* Qt = (_Float16*)(ws + 262144);        // 4*4096*32*2 = 1 MB
    _Float16* Kt = (_Float16*)(ws + 1310720);       // 1 MB
    _Float16* Vh = (_Float16*)(ws + 2359296);       // 4*256*4096*2 = 8 MB

    prep_kernel<<<dim3(320), 64, 0, stream>>>(Wq, bq, Wk, bk, Wv, bv, Wh, bh);
    proj_kernel<<<dim3(NN / 32, BB), 512, 0, stream>>>(x, Wh, bh, Qt, Kt, Vh);
    attn_kernel<<<dim3(NN / 64, 2, BB), 256, 0, stream>>>(x, Qt, Kt, Vh, out);
}

// Round 12
// 193.142 us; speedup vs baseline: 1.7438x; 1.3126x over previous
//
#include <hip/hip_runtime.h>
#include <math.h>

#define BB 4
#define CC 256
#define NN 4096
#define DQ 32
#define LOG2E 1.44269504f

typedef _Float16 half8 __attribute__((ext_vector_type(8)));
typedef _Float16 half4 __attribute__((ext_vector_type(4)));
typedef float float4v __attribute__((ext_vector_type(4)));

// ---------------- prep: W -> f16 (log2e folded into Wq/bq) ----------------
__global__ __launch_bounds__(64) void prep_kernel(
    const float* __restrict__ Wq, const float* __restrict__ bq,
    const float* __restrict__ Wk, const float* __restrict__ bk,
    const float* __restrict__ Wv, const float* __restrict__ bv,
    _Float16* __restrict__ Wh, float* __restrict__ bh)
{
    int o = blockIdx.x, t = threadIdx.x;
    const float* src; float scale = 1.0f, bias;
    if (o < DQ)            { src = Wq + o * CC;        scale = LOG2E; bias = bq[o] * LOG2E; }
    else if (o < 2 * DQ)   { src = Wk + (o - DQ) * CC;                bias = bk[o - DQ]; }
    else                   { src = Wv + (o - 2 * DQ) * CC;            bias = bv[o - 2 * DQ]; }
    float4 v = *(const float4*)(src + t * 4);
    half4 h = { (_Float16)(v.x * scale), (_Float16)(v.y * scale),
                (_Float16)(v.z * scale), (_Float16)(v.w * scale) };
    *(half4*)(Wh + o * CC + t * 4) = h;
    if (t == 0) bh[o] = bias;
}

// ---------------- proj: 4-wave, 32-pixel tile, VECTOR LDS writes ----------------
// r5-verified structure; two targeted fixes:
//  (1) staging: thread owns 4 consecutive c x 8 n -> 8 half4 writes (was 32 b16)
//  (2) V pairs use swapped-operand MFMA (bf as A, af as B): acc rows become n,
//      col becomes o=i16 -> os_v epilogue is 1 half4 write per nt (was 4 b16).
//      Same loaded fragments; bias broadcast per-lane. QK pairs unchanged.
__global__ __launch_bounds__(256) void proj_kernel(
    const float* __restrict__ x, const _Float16* __restrict__ Wh,
    const float* __restrict__ bh,
    _Float16* __restrict__ Qt, _Float16* __restrict__ Kt,
    _Float16* __restrict__ Vh)
{
    __shared__ _Float16 xl[32 * 256];     // [n][c], chunk-of-8 XOR swizzle: chunk' = (c>>3) ^ n
    __shared__ _Float16 os_qk[32 * 72];   // [n][o<64 + pad]
    __shared__ _Float16 os_v[256 * 40];   // [c][n + pad]

    const int tid = threadIdx.x;
    const int lane = tid & 63, w = tid >> 6;
    const int i16 = lane & 15, q = lane >> 4;
    const int n0 = blockIdx.x * 32, b = blockIdx.y;

    // stage x tile transposed to f16 [n][c]: thread = (c-quad g, n-octet jn)
    const float* xb = x + (size_t)b * CC * NN + n0;
    {
        const int g = tid >> 2;           // 0..63 -> c = 4g..4g+3
        const int jn = tid & 3;           // 0..3  -> n = 8jn..8jn+7
        const float* xq = xb + (size_t)(4 * g) * NN + 8 * jn;
        float4 v[4][2];
        #pragma unroll
        for (int cc = 0; cc < 4; ++cc)
            #pragma unroll
            for (int h = 0; h < 2; ++h)
                v[cc][h] = *(const float4*)(xq + (size_t)cc * NN + 4 * h);
        const int chunkc = g >> 1, cl = 4 * (g & 1);
        #pragma unroll
        for (int h = 0; h < 2; ++h)
            #pragma unroll
            for (int e = 0; e < 4; ++e) {
                int n = 8 * jn + 4 * h + e;
                const float* v0 = (const float*)&v[0][h];
                const float* v1 = (const float*)&v[1][h];
                const float* v2 = (const float*)&v[2][h];
                const float* v3 = (const float*)&v[3][h];
                half4 hv = { (_Float16)v0[e], (_Float16)v1[e],
                             (_Float16)v2[e], (_Float16)v3[e] };
                *(half4*)&xl[n * 256 + ((chunkc ^ n) * 8) + cl] = hv;
            }
    }

    // bias init: QK pairs (og<64): per-row o = og+4q+r; V pairs: broadcast bh[og+i16]
    float4v acc[5][2];
    const int obase = 80 * w;
    #pragma unroll
    for (int ot = 0; ot < 5; ++ot) {
        int og = obase + 16 * ot;
        if (og < 64) {
            float4 b4 = *(const float4*)(bh + og + 4 * q);
            #pragma unroll
            for (int nt = 0; nt < 2; ++nt)
                acc[ot][nt] = (float4v){b4.x, b4.y, b4.z, b4.w};
        } else {
            float bv_ = bh[og + i16];
            #pragma unroll
            for (int nt = 0; nt < 2; ++nt)
                acc[ot][nt] = (float4v){bv_, bv_, bv_, bv_};
        }
    }
    __syncthreads();

    // K loop: 8 steps of 32 channels; V pairs use swapped operands
    #pragma unroll
    for (int k = 0; k < 8; ++k) {
        half8 af[5], bf[2];
        #pragma unroll
        for (int ot = 0; ot < 5; ++ot)
            af[ot] = *(const half8*)(Wh + (size_t)(obase + 16 * ot + i16) * CC + k * 32 + 8 * q);
        #pragma unroll
        for (int nt = 0; nt < 2; ++nt) {
            int n = 16 * nt + i16;
            bf[nt] = *(const half8*)&xl[n * 256 + (((4 * k + q) ^ n) * 8)];
        }
        #pragma unroll
        for (int ot = 0; ot < 5; ++ot) {
            int og = obase + 16 * ot;
            #pragma unroll
            for (int nt = 0; nt < 2; ++nt) {
                if (og < 64)
                    acc[ot][nt] = __builtin_amdgcn_mfma_f32_16x16x32_f16(af[ot], bf[nt], acc[ot][nt], 0, 0, 0);
                else
                    acc[ot][nt] = __builtin_amdgcn_mfma_f32_16x16x32_f16(bf[nt], af[ot], acc[ot][nt], 0, 0, 0);
            }
        }
    }

    // epilogue: all-vector writes into transpose buffers
    #pragma unroll
    for (int ot = 0; ot < 5; ++ot) {
        int og = obase + 16 * ot;
        #pragma unroll
        for (int nt = 0; nt < 2; ++nt) {
            half4 hv = { (_Float16)acc[ot][nt][0], (_Float16)acc[ot][nt][1],
                         (_Float16)acc[ot][nt][2], (_Float16)acc[ot][nt][3] };
            if (og < 64) {   // rows o=og+4q+r, col n=16nt+i16
                int n = 16 * nt + i16;
                *(half4*)&os_qk[n * 72 + og + 4 * q] = hv;
            } else {         // swapped: rows n=16nt+4q+r, col c=og-64+i16
                int c = og - 64 + i16;
                *(half4*)&os_v[c * 40 + 16 * nt + 4 * q] = hv;
            }
        }
    }
    __syncthreads();

    // coalesced global stores
    _Float16* Qtb = Qt + (size_t)b * NN * DQ;
    _Float16* Ktb = Kt + (size_t)b * NN * DQ;
    {
        int n = tid >> 3, p = tid & 7;
        half8 hv = *(const half8*)&os_qk[n * 72 + 8 * p];
        if (p < 4) *(half8*)(Qtb + (size_t)(n0 + n) * DQ + 8 * p) = hv;
        else       *(half8*)(Ktb + (size_t)(n0 + n) * DQ + 8 * (p - 4)) = hv;
    }
    _Float16* Vb = Vh + (size_t)b * CC * NN;
    #pragma unroll
    for (int u = 0; u < 4; ++u) {
        int c = u * 64 + (tid >> 2), p = tid & 3;
        half8 hv = *(const half8*)&os_v[c * 40 + 8 * p];
        *(half8*)(Vb + (size_t)c * NN + n0 + 8 * p) = hv;
    }
}

// ---------------- attn: max-only prepass + pipelined PV with inline l (r5-verified) ----------------
__global__ __launch_bounds__(256) void attn_kernel(
    const float* __restrict__ x,
    const _Float16* __restrict__ Qt, const _Float16* __restrict__ Kt,
    const _Float16* __restrict__ Vh,
    float* __restrict__ out)
{
    __shared__ _Float16 k_lds[2][64 * 32];    // [j][d], d-chunk ^= (j&3)
    __shared__ _Float16 v_lds[3][128 * 64];   // [c][j], j-chunk ^= (c&7)
    __shared__ _Float16 ps[2][64 * 72];       // P': [i][j + pad]
    __shared__ float    stx[4][64];           // cross-wave exchange (m, then l)

    const int tid = threadIdx.x;
    const int w = tid >> 6, lane = tid & 63;
    const int i16 = lane & 15, q = lane >> 4;
    const int i0 = blockIdx.x * 64, cs = blockIdx.y, b = blockIdx.z;
    const int c0 = cs * 128;

    const _Float16* Ktb = Kt + (size_t)b * NN * DQ;
    const _Float16* Vb  = Vh + (size_t)b * CC * NN + (size_t)c0 * NN;

    half8 qb[4];
    {
        const _Float16* Qtb = Qt + (size_t)b * NN * DQ;
        #pragma unroll
        for (int it = 0; it < 4; ++it)
            qb[it] = *(const half8*)(Qtb + (size_t)(i0 + 16 * it + i16) * DQ + 8 * q);
    }

    // ---- pass M: per-query max over this wave's key quarter (no exp2) ----
    float mA[4] = {-INFINITY, -INFINITY, -INFINITY, -INFINITY};
    {
        const _Float16* kq = Ktb + (size_t)(1024 * w) * DQ;
        half8 kf0 = *(const half8*)(kq + (size_t)i16 * DQ + 8 * q);
        half8 kf1 = *(const half8*)(kq + (size_t)(16 + i16) * DQ + 8 * q);
        for (int t = 0; t < 64; t += 2) {
            {
                half8 ka = kf0;
                if (t + 2 < 64)
                    kf0 = *(const half8*)(kq + (size_t)(16 * (t + 2) + i16) * DQ + 8 * q);
                #pragma unroll
                for (int it = 0; it < 4; ++it) {
                    float4v z = {0.f, 0.f, 0.f, 0.f};
                    float4v s = __builtin_amdgcn_mfma_f32_16x16x32_f16(ka, qb[it], z, 0, 0, 0);
                    mA[it] = fmaxf(mA[it], fmaxf(fmaxf(s[0], s[1]), fmaxf(s[2], s[3])));
                }
            }
            {
                half8 ka = kf1;
                if (t + 3 < 64)
                    kf1 = *(const half8*)(kq + (size_t)(16 * (t + 3) + i16) * DQ + 8 * q);
                #pragma unroll
                for (int it = 0; it < 4; ++it) {
                    float4v z = {0.f, 0.f, 0.f, 0.f};
                    float4v s = __builtin_amdgcn_mfma_f32_16x16x32_f16(ka, qb[it], z, 0, 0, 0);
                    mA[it] = fmaxf(mA[it], fmaxf(fmaxf(s[0], s[1]), fmaxf(s[2], s[3])));
                }
            }
        }
        #pragma unroll
        for (int it = 0; it < 4; ++it) {
            mA[it] = fmaxf(mA[it], __shfl_xor(mA[it], 16, 64));
            mA[it] = fmaxf(mA[it], __shfl_xor(mA[it], 32, 64));
        }
        if (q == 0) {
            #pragma unroll
            for (int it = 0; it < 4; ++it)
                stx[w][16 * it + i16] = mA[it];
        }
    }
    __syncthreads();

    float m2v[4];
    #pragma unroll
    for (int it = 0; it < 4; ++it) {
        int qrow = 16 * it + i16;
        m2v[it] = fmaxf(fmaxf(stx[0][qrow], stx[1][qrow]),
                        fmaxf(stx[2][qrow], stx[3][qrow]));
    }

    // ---- pass B: software-pipelined PV loop (round-3 verified) + inline l ----
    float4v O[2][4];
    #pragma unroll
    for (int ct = 0; ct < 2; ++ct)
        #pragma unroll
        for (int it = 0; it < 4; ++it)
            O[ct][it] = (float4v){0.f, 0.f, 0.f, 0.f};
    float lB[4] = {0.f, 0.f, 0.f, 0.f};

    const int jK = tid >> 2, dgK = tid & 3;      // K: 1 half8/thread
    const int cbV = tid >> 3, jgV = tid & 7;     // V: 4 half8/thread
    const int kaddr = jK * 32 + ((dgK ^ (jK & 3)) * 8);
    int vaddr[4];
    #pragma unroll
    for (int u = 0; u < 4; ++u) {
        int c = u * 32 + cbV;
        vaddr[u] = c * 64 + ((jgV ^ (c & 7)) * 8);
    }

    half8 kv, vv[4];
    kv = *(const half8*)(Ktb + (size_t)jK * DQ + 8 * dgK);
    #pragma unroll
    for (int u = 0; u < 4; ++u)
        vv[u] = *(const half8*)(Vb + (size_t)(u * 32 + cbV) * NN + 8 * jgV);
    *(half8*)&k_lds[0][kaddr] = kv;
    #pragma unroll
    for (int u = 0; u < 4; ++u)
        *(half8*)&v_lds[0][vaddr[u]] = vv[u];
    kv = *(const half8*)(Ktb + (size_t)(64 + jK) * DQ + 8 * dgK);
    #pragma unroll
    for (int u = 0; u < 4; ++u)
        vv[u] = *(const half8*)(Vb + (size_t)(u * 32 + cbV) * NN + 64 + 8 * jgV);

    for (int t = 0; t <= 64; ++t) {
        __syncthreads();
        // stage tile t+1 from regs (loaded at iter t-1)
        if (t < 63) {
            *(half8*)&k_lds[(t + 1) & 1][kaddr] = kv;
            const int vn = (t + 1) % 3;
            #pragma unroll
            for (int u = 0; u < 4; ++u)
                *(half8*)&v_lds[vn][vaddr[u]] = vv[u];
        }
        // issue prefetch of tile t+2 (drained by next barrier; covers S+PV)
        if (t < 62) {
            int jn = (t + 2) * 64;
            kv = *(const half8*)(Ktb + (size_t)(jn + jK) * DQ + 8 * dgK);
            #pragma unroll
            for (int u = 0; u < 4; ++u)
                vv[u] = *(const half8*)(Vb + (size_t)(u * 32 + cbV) * NN + jn + 8 * jgV);
        }
        // PV(t-1): inputs were completed before this iter's barrier
        if (t > 0) {
            const _Float16* psp = ps[(t - 1) & 1];
            const _Float16* vp  = v_lds[(t - 1) % 3];
            half8 pb[2][4];
            #pragma unroll
            for (int ks = 0; ks < 2; ++ks)
                #pragma unroll
                for (int it = 0; it < 4; ++it)
                    pb[ks][it] = *(const half8*)&psp[(16 * it + i16) * 72 + 32 * ks + 8 * q];
            __builtin_amdgcn_s_setprio(1);
            #pragma unroll
            for (int ct = 0; ct < 2; ++ct) {
                int c = 32 * w + 16 * ct + i16;
                #pragma unroll
                for (int ks = 0; ks < 2; ++ks) {
                    int g = 4 * ks + q;
                    half8 va = *(const half8*)&vp[c * 64 + ((g ^ (c & 7)) * 8)];
                    #pragma unroll
                    for (int it = 0; it < 4; ++it)
                        O[ct][it] = __builtin_amdgcn_mfma_f32_16x16x32_f16(va, pb[ks][it], O[ct][it], 0, 0, 0);
                }
            }
            __builtin_amdgcn_s_setprio(0);
        }
        // S(t) -> ps[t&1]; accumulate l from the f32 P' values
        if (t < 64) {
            int j = 16 * w + i16;
            half8 ka = *(const half8*)&k_lds[t & 1][j * 32 + ((q ^ (j & 3)) * 8)];
            _Float16* psc = ps[t & 1];
            #pragma unroll
            for (int it = 0; it < 4; ++it) {
                float4v z = {0.f, 0.f, 0.f, 0.f};
                float4v s = __builtin_amdgcn_mfma_f32_16x16x32_f16(ka, qb[it], z, 0, 0, 0);
                float p0 = exp2f(s[0] - m2v[it]);
                float p1 = exp2f(s[1] - m2v[it]);
                float p2 = exp2f(s[2] - m2v[it]);
                float p3 = exp2f(s[3] - m2v[it]);
                lB[it] += (p0 + p1) + (p2 + p3);
                half4 hv = { (_Float16)p0, (_Float16)p1, (_Float16)p2, (_Float16)p3 };
                *(half4*)&psc[(16 * it + i16) * 72 + 16 * w + 4 * q] = hv;
            }
        }
    }

    // reduce l: over q-quads (keys 4q+r), then across waves (key strips)
    #pragma unroll
    for (int it = 0; it < 4; ++it) {
        lB[it] += __shfl_xor(lB[it], 16, 64);
        lB[it] += __shfl_xor(lB[it], 32, 64);
    }
    if (q == 0) {
        #pragma unroll
        for (int it = 0; it < 4; ++it)
            stx[w][16 * it + i16] = lB[it];
    }
    __syncthreads();
    float linv[4];
    #pragma unroll
    for (int it = 0; it < 4; ++it) {
        int qrow = 16 * it + i16;
        linv[it] = 1.0f / ((stx[0][qrow] + stx[1][qrow]) + (stx[2][qrow] + stx[3][qrow]));
    }

    // epilogue: O * (1/l) + residual
    const float* xb = x + (size_t)b * CC * NN;
    float* ob = out + (size_t)b * CC * NN;
    #pragma unroll
    for (int ct = 0; ct < 2; ++ct)
        #pragma unroll
        for (int it = 0; it < 4; ++it)
            #pragma unroll
            for (int r = 0; r < 4; ++r) {
                int c = c0 + 32 * w + 16 * ct + 4 * q + r;
                size_t idx = (size_t)c * NN + i0 + 16 * it + i16;
                ob[idx] = xb[idx] + O[ct][it][r] * linv[it];
            }
}

extern "C" void kernel_launch(void* const* d_in, const int* in_sizes, int n_in,
                              void* d_out, int out_size, void* d_ws, size_t ws_size,
                              hipStream_t stream) {
    const float* x  = (const float*)d_in[0];
    const float* Wq = (const float*)d_in[1];
    const float* bq = (const float*)d_in[2];
    const float* Wk = (const float*)d_in[3];
    const float* bk = (const float*)d_in[4];
    const float* Wv = (const float*)d_in[5];
    const float* bv = (const float*)d_in[6];
    float* out = (float*)d_out;

    char* ws = (char*)d_ws;
    _Float16* Wh = (_Float16*)(ws);                 // 320*256*2 = 163840
    float*    bh = (float*)(ws + 163840);           // 1280
    _Float16* Qt = (_Float16*)(ws + 262144);        // 4*4096*32*2 = 1 MB
    _Float16* Kt = (_Float16*)(ws + 1310720);       // 1 MB
    _Float16* Vh = (_Float16*)(ws + 2359296);       // 4*256*4096*2 = 8 MB

    prep_kernel<<<dim3(320), 64, 0, stream>>>(Wq, bq, Wk, bk, Wv, bv, Wh, bh);
    proj_kernel<<<dim3(NN / 32, BB), 256, 0, stream>>>(x, Wh, bh, Qt, Kt, Vh);
    attn_kernel<<<dim3(NN / 64, 2, BB), 256, 0, stream>>>(x, Qt, Kt, Vh, out);
}